// Round 14
// baseline (200.988 us; speedup 1.0000x reference)
//
#include <hip/hip_runtime.h>
#include <hip/hip_fp16.h>

// DepTreeLSTM on MI355X — R14 = best-measured composition:
//   prep_kernel : R9's fused pack(768 blocks) + build_x16(2560 blocks).
//   xp_gemm     : R7's verbatim M=128/grid-256 LDS-staged GEMM (fp16 A from
//                 x16 table) — measured best xp shape (R7 non-tree = 100 µs).
//   tree_kernel : R13 byte-identical (verified 82.5 µs, fragile codegen —
//                 do not perturb; R11 lesson).

typedef _Float16 f16x8 __attribute__((ext_vector_type(8)));
typedef _Float16 f16x4 __attribute__((ext_vector_type(4)));
typedef float f32x4 __attribute__((ext_vector_type(4)));

#define NP 16   // pairs per tree block

__device__ __forceinline__ void async16(const void* g, void* l) {
    __builtin_amdgcn_global_load_lds(
        (const __attribute__((address_space(1))) void*)g,
        (__attribute__((address_space(3))) void*)l, 16, 0, 0);
}
__device__ __forceinline__ float sigm(float x) {
    return __builtin_amdgcn_rcpf(1.f + __expf(-x));
}
__device__ __forceinline__ float ftanh(float x) {
    float a = __expf(-2.f * fabsf(x));
    return copysignf((1.f - a) * __builtin_amdgcn_rcpf(1.f + a), x);
}
__device__ __forceinline__ void lgkm_barrier() {
    asm volatile("s_waitcnt lgkmcnt(0)\n\ts_barrier" ::: "memory");
}

// ---- prep: blocks [0,768) pack weights/bias; [768,3328) build x16 ----
__global__ __launch_bounds__(256) void prep_kernel(
    const float* __restrict__ tok, const float* __restrict__ oh,
    const float* __restrict__ dep,
    const float* __restrict__ Wi_u, const float* __restrict__ Ui_u,
    const float* __restrict__ bi_u, const float* __restrict__ Wf_u,
    const float* __restrict__ Uf_u, const float* __restrict__ bf_u,
    const float* __restrict__ Wi_d, const float* __restrict__ Ui_d,
    const float* __restrict__ bi_d, const float* __restrict__ Wf_d,
    const float* __restrict__ Uf_d, const float* __restrict__ bf_d,
    _Float16* __restrict__ Bx, _Float16* __restrict__ Upk,
    float* __restrict__ pb, _Float16* __restrict__ x16)
{
    const int b = blockIdx.x;
    if (b < 768) {
        int idx = b * 256 + threadIdx.x;          // 196608 total
        if (idx < 512) {
            int d = idx >> 8, c = idx & 255, u = c >> 2, g = c & 3;
            const float* bio = d ? bi_d : bi_u;
            const float* bf  = d ? bf_d : bf_u;
            pb[idx] = (g < 3) ? bio[g * 64 + u] : bf[u];
        }
        if (idx < 163840) {                        // Bx: [dir][col256][k320]
            int d = idx / 81920, r1 = idx % 81920;
            int c = r1 / 320, k = r1 % 320, u = c >> 2, g = c & 3;
            const float* Wio = d ? Wi_d : Wi_u;
            const float* Wf  = d ? Wf_d : Wf_u;
            Bx[idx] = (_Float16)((g < 3) ? Wio[k * 192 + g * 64 + u]
                                         : Wf[k * 64 + u]);
        } else {                                   // Upk: 2*4*64*64
            int j = idx - 163840;
            int d = j >> 14, r2 = j & 16383;
            int g = r2 >> 12, u = (r2 >> 6) & 63, k = r2 & 63;
            const float* Uio = d ? Ui_d : Ui_u;
            const float* Uf  = d ? Uf_d : Uf_u;
            Upk[j] = (_Float16)((g < 3) ? Uio[k * 192 + g * 64 + u]
                                        : Uf[k * 64 + u]);
        }
    } else {
        int idx = (b - 768) * 256 + threadIdx.x;   // 16384 bt * 40 granules
        int bt = idx / 40, g = idx % 40;
        const float* src = (g < 32) ? tok + (size_t)bt * 256 + g * 8
                         : (g < 36) ? oh  + (size_t)bt * 32 + (g - 32) * 8
                                    : dep + (size_t)bt * 32 + (g - 36) * 8;
        float4 f0 = *(const float4*)src;
        float4 f1 = *(const float4*)(src + 4);
        f16x8 v;
        v[0] = (_Float16)f0.x; v[1] = (_Float16)f0.y;
        v[2] = (_Float16)f0.z; v[3] = (_Float16)f0.w;
        v[4] = (_Float16)f1.x; v[5] = (_Float16)f1.y;
        v[6] = (_Float16)f1.z; v[7] = (_Float16)f1.w;
        *(f16x8*)(x16 + (size_t)bt * 320 + g * 8) = v;
    }
}

// ---- XP = x16 @ Bx + pb : M=128, K=320, N=256 per dir; grid 256 ----
__global__ __launch_bounds__(256) void xp_gemm(
    const _Float16* __restrict__ x16, const _Float16* __restrict__ Bx,
    const float* __restrict__ pb, _Float16* __restrict__ XP)
{
    __shared__ _Float16 At[128 * 64];
    __shared__ _Float16 Btl[256 * 64];
    const int mt = blockIdx.x & 127, dir = blockIdx.x >> 7;
    const int tid = threadIdx.x, lane = tid & 63, w = tid >> 6;
    const int l15 = lane & 15, qd = lane >> 4;
    const int rsub = lane >> 3, pg = lane & 7;
    const int koff = ((pg - rsub) & 7) * 8;
    const int rowbase = mt * 128;
    const _Float16* Bb = Bx + (size_t)dir * 81920 + (w * 64 + rsub) * 320 + koff;

    f32x4 acc[8][4];
    #pragma unroll
    for (int i = 0; i < 8; ++i)
        #pragma unroll
        for (int j = 0; j < 4; ++j) acc[i][j] = (f32x4){0.f, 0.f, 0.f, 0.f};

    #pragma unroll
    for (int kt = 0; kt < 5; ++kt) {
        #pragma unroll
        for (int is = 0; is < 4; ++is)
            async16(x16 + (size_t)(rowbase + w * 32 + is * 8 + rsub) * 320
                        + kt * 64 + koff,
                    &At[(w * 32 + is * 8) * 64]);
        #pragma unroll
        for (int is = 0; is < 8; ++is)
            async16(Bb + (size_t)is * 8 * 320 + kt * 64,
                    &Btl[(w * 64 + is * 8) * 64]);
        __syncthreads();
        #pragma unroll
        for (int s = 0; s < 2; ++s) {
            const int g0 = s * 4 + qd;
            f16x8 af[8];
            #pragma unroll
            for (int i = 0; i < 8; ++i) {
                int R = i * 16 + l15;
                af[i] = *(const f16x8*)&At[R * 64 + ((g0 + R) & 7) * 8];
            }
            #pragma unroll
            for (int j = 0; j < 4; ++j) {
                int C = j * 64 + w * 16 + l15;
                f16x8 bf = *(const f16x8*)&Btl[C * 64 + ((g0 + C) & 7) * 8];
                #pragma unroll
                for (int i = 0; i < 8; ++i)
                    acc[i][j] = __builtin_amdgcn_mfma_f32_16x16x32_f16(
                        af[i], bf, acc[i][j], 0, 0, 0);
            }
        }
        __syncthreads();
    }
    #pragma unroll
    for (int i = 0; i < 8; ++i)
        #pragma unroll
        for (int j = 0; j < 4; ++j) {
            int colp = j * 64 + w * 16 + l15;
            float bias = pb[dir * 256 + colp];
            #pragma unroll
            for (int r = 0; r < 4; ++r) {
                int row = rowbase + i * 16 + qd * 4 + r;
                XP[(size_t)row * 512 + dir * 256 + colp] =
                    (_Float16)(acc[i][j][r] + bias);
            }
        }
}

// ---- gather XP preacts for one side of one level into registers ----
template<int RPP>
__device__ __forceinline__ void gather_xp(
    const char* __restrict__ XPd, const int (*btl)[NP],
    int p0, int p1, int unit, int qd, f16x4* px)
{
    #pragma unroll
    for (int i = 0; i < RPP; ++i)
        #pragma unroll
        for (int r = 0; r < 4; ++r) {
            int row = i * 16 + qd * 4 + r;
            int pl  = (RPP == 2) ? (row >> 1) : row;
            int pos = (RPP == 2) ? ((row & 1) ? p1 : p0) : p0;
            px[i * 4 + r] = *(const f16x4*)(XPd + btl[pos][pl] + unit * 8);
        }
}

// ---- compute one side of one level (state read parity -> write parity) ----
template<int RPP>
__device__ __forceinline__ void side_level(
    const f16x8 (*bfr)[4], const f16x4* px,
    const _Float16 (*hR)[68], const _Float16 (*cR)[68],
    _Float16 (*hW)[68], _Float16 (*cW)[68],
    float* __restrict__ out, int pair0,
    int rs0, int rs1, int oc0, int oc1,
    int unit, int l15, int qd)
{
    f32x4 acc[RPP][4];
    #pragma unroll
    for (int i = 0; i < RPP; ++i)
        #pragma unroll
        for (int r = 0; r < 4; ++r) {
            f16x4 g4 = px[i * 4 + r];
            acc[i][0][r] = (float)g4[0];
            acc[i][1][r] = (float)g4[1];
            acc[i][2][r] = (float)g4[2];
            acc[i][3][r] = (float)g4[3];
        }

    if (rs0 >= 0) {
        #pragma unroll
        for (int s = 0; s < 2; ++s)
            #pragma unroll
            for (int i = 0; i < RPP; ++i) {
                int R = i * 16 + l15;
                int arow = (RPP == 2) ? ((R & ~1) | ((R & 1) ? rs1 : rs0))
                                      : (R * 2 + rs0);
                f16x8 af = *(const f16x8*)&hR[arow][s * 32 + qd * 8];
                #pragma unroll
                for (int g = 0; g < 4; ++g)
                    acc[i][g] = __builtin_amdgcn_mfma_f32_16x16x32_f16(
                        af, bfr[s][g], acc[i][g], 0, 0, 0);
            }
    }

    #pragma unroll
    for (int i = 0; i < RPP; ++i)
        #pragma unroll
        for (int r = 0; r < 4; ++r) {
            int row = i * 16 + qd * 4 + r;
            int pl   = (RPP == 2) ? (row >> 1) : row;
            int slot = (RPP == 2) ? (row & 1) : 0;
            int rs = slot ? rs1 : rs0;
            float cin = (rs >= 0) ? (float)cR[pl * 2 + rs][unit] : 0.f;
            float I = acc[i][0][r], O = acc[i][1][r],
                  Uu = acc[i][2][r], F = acc[i][3][r];
            float cn = sigm(I) * ftanh(Uu) + sigm(F) * cin;
            float h  = sigm(O) * ftanh(cn);
            int oc = slot ? oc1 : oc0;
            if (oc >= 0) {
                out[(size_t)(pair0 + pl) * 192 + oc + unit] = h;
            } else {
                hW[pl * 2 + slot][unit] = (_Float16)h;
                cW[pl * 2 + slot][unit] = (_Float16)cn;
            }
        }
}

// ---- root (up, t=8): h7/c7 from par0 slot0; h9/c9 from par1 slot1 ----
__device__ __forceinline__ void root_level(
    const f16x8 (*bfr)[4], const f16x4* px,
    const _Float16 (*hR0)[68], const _Float16 (*cR0)[68],
    const _Float16 (*hR1)[68], const _Float16 (*cR1)[68],
    float* __restrict__ out, int pair0, int unit, int l15, int qd)
{
    f32x4 aio[3], aF7, aF9;
    #pragma unroll
    for (int r = 0; r < 4; ++r) {
        f16x4 g4 = px[r];
        aio[0][r] = (float)g4[0];
        aio[1][r] = (float)g4[1];
        aio[2][r] = (float)g4[2];
        aF7[r] = (float)g4[3];
        aF9[r] = (float)g4[3];
    }
    #pragma unroll
    for (int s = 0; s < 2; ++s) {
        f16x8 v7 = *(const f16x8*)&hR0[l15 * 2 + 0][s * 32 + qd * 8];
        f16x8 v9 = *(const f16x8*)&hR1[l15 * 2 + 1][s * 32 + qd * 8];
        f16x8 vs = v7 + v9;
        aio[0] = __builtin_amdgcn_mfma_f32_16x16x32_f16(vs, bfr[s][0], aio[0], 0, 0, 0);
        aio[1] = __builtin_amdgcn_mfma_f32_16x16x32_f16(vs, bfr[s][1], aio[1], 0, 0, 0);
        aio[2] = __builtin_amdgcn_mfma_f32_16x16x32_f16(vs, bfr[s][2], aio[2], 0, 0, 0);
        aF7 = __builtin_amdgcn_mfma_f32_16x16x32_f16(v7, bfr[s][3], aF7, 0, 0, 0);
        aF9 = __builtin_amdgcn_mfma_f32_16x16x32_f16(v9, bfr[s][3], aF9, 0, 0, 0);
    }
    #pragma unroll
    for (int r = 0; r < 4; ++r) {
        int pl = qd * 4 + r;
        float c7 = (float)cR0[pl * 2 + 0][unit];
        float c9 = (float)cR1[pl * 2 + 1][unit];
        float cn = sigm(aio[0][r]) * ftanh(aio[2][r])
                 + sigm(aF7[r]) * c7 + sigm(aF9[r]) * c9;
        float h = sigm(aio[1][r]) * ftanh(cn);
        out[(size_t)(pair0 + pl) * 192 + unit] = h;
    }
}

__global__ __launch_bounds__(256, 2) void tree_kernel(
    const int* __restrict__ nb, const int* __restrict__ nt,
    const _Float16* __restrict__ XP, const _Float16* __restrict__ Upk,
    float* __restrict__ out)
{
    __shared__ _Float16 hS[2][2][NP * 2][68];  // [parity][dir][pl*2+slot][unit]
    __shared__ _Float16 cS[2][2][NP * 2][68];
    __shared__ int btl[16][NP];                // byte offsets into XP rows

    const int tid = threadIdx.x, lane = tid & 63, w = tid >> 6;
    const int l15 = lane & 15, qd = lane >> 4;
    const int unit = w * 16 + l15;
    const int pair0 = blockIdx.x * NP;

    {
        int pos = tid >> 4, pl = tid & 15;
        int node = (pair0 + pl) * 16 + pos;
        btl[pos][pl] = (nb[node] * 512 + nt[node]) * 1024;
    }

    // hoist U fragments for both dirs (register-resident, 64 VGPRs)
    f16x8 bU[2][4], bD[2][4];
    #pragma unroll
    for (int s = 0; s < 2; ++s)
        #pragma unroll
        for (int g = 0; g < 4; ++g) {
            bU[s][g] = *(const f16x8*)(Upk + (g * 64 + unit) * 64 + s * 32 + qd * 8);
            bD[s][g] = *(const f16x8*)(Upk + 16384 + (g * 64 + unit) * 64 + s * 32 + qd * 8);
        }

    __syncthreads();   // btl visible

    const char* XPu = (const char*)XP;
    const char* XPdn = XPu + 512;

    f16x4 pxu[2][8], pxd[8];
    gather_xp<2>(XPu, btl, 0, 15, unit, qd, pxu[0]);

    #pragma unroll
    for (int t = 0; t < 9; ++t) {
        const int pt = t & 1, pw = pt ^ 1;
        // prefetch down side for this level
        if (t == 0)      gather_xp<1>(XPdn, btl, 8, 8, unit, qd, pxd);
        else if (t == 8) gather_xp<1>(XPdn, btl, 0, 0, unit, qd, pxd);
        else             gather_xp<2>(XPdn, btl, 8 - t, 8 + t, unit, qd, pxd);
        // prefetch up side for next level (crosses the barrier)
        if (t < 6)       gather_xp<2>(XPu, btl, t + 1, 14 - t, unit, qd, pxu[pw]);
        else if (t == 6) gather_xp<1>(XPu, btl, 7, 7, unit, qd, pxu[pw]);
        else if (t == 7) gather_xp<1>(XPu, btl, 8, 8, unit, qd, pxu[pw]);

        // ---- up ----
        if (t < 7)
            side_level<2>(bU, pxu[pt], hS[pt][0], cS[pt][0],
                          hS[pw][0], cS[pw][0], out, pair0,
                          t ? 0 : -1, t ? 1 : -1, -1, -1, unit, l15, qd);
        else if (t == 7)
            side_level<1>(bU, pxu[pt], hS[pt][0], cS[pt][0],
                          hS[pw][0], cS[pw][0], out, pair0,
                          0, 0, -1, -1, unit, l15, qd);
        else
            root_level(bU, pxu[pt], hS[0][0], cS[0][0], hS[1][0], cS[1][0],
                       out, pair0, unit, l15, qd);

        // ---- down ----
        if (t == 0)
            side_level<1>(bD, pxd, hS[pt][1], cS[pt][1],
                          hS[pw][1], cS[pw][1], out, pair0,
                          -1, -1, -1, -1, unit, l15, qd);
        else if (t == 8)
            side_level<1>(bD, pxd, hS[pt][1], cS[pt][1],
                          hS[pw][1], cS[pw][1], out, pair0,
                          0, 0, 64, 64, unit, l15, qd);
        else
            side_level<2>(bD, pxd, hS[pt][1], cS[pt][1],
                          hS[pw][1], cS[pw][1], out, pair0,
                          0, (t == 1) ? 0 : 1, -1, (t == 7) ? 128 : -1,
                          unit, l15, qd);

        lgkm_barrier();   // LDS writes visible; global gathers stay in flight
    }
}

extern "C" void kernel_launch(void* const* d_in, const int* in_sizes, int n_in,
                              void* d_out, int out_size, void* d_ws, size_t ws_size,
                              hipStream_t stream)
{
    const float* tok  = (const float*)d_in[0];
    const float* ohp  = (const float*)d_in[1];
    const float* dep  = (const float*)d_in[2];
    const int*   nb   = (const int*)d_in[3];
    const int*   nt   = (const int*)d_in[4];
    const float* Wi_u = (const float*)d_in[13];
    const float* Ui_u = (const float*)d_in[14];
    const float* bi_u = (const float*)d_in[15];
    const float* Wf_u = (const float*)d_in[16];
    const float* Uf_u = (const float*)d_in[17];
    const float* bf_u = (const float*)d_in[18];
    const float* Wi_d = (const float*)d_in[19];
    const float* Ui_d = (const float*)d_in[20];
    const float* bi_d = (const float*)d_in[21];
    const float* Wf_d = (const float*)d_in[22];
    const float* Uf_d = (const float*)d_in[23];
    const float* bf_d = (const float*)d_in[24];

    char* ws = (char*)d_ws;
    _Float16* Bx  = (_Float16*)(ws);                    // 320 KB
    _Float16* Upk = (_Float16*)(ws + 0x50000);          // 64 KB
    float*    pb  = (float*)   (ws + 0x60000);          // 2 KB
    _Float16* x16 = (_Float16*)(ws + (1u  << 20));      // 10 MB
    _Float16* XP  = (_Float16*)(ws + (12u << 20));      // 16 MB
    float* out = (float*)d_out;

    prep_kernel<<<3328, 256, 0, stream>>>(tok, ohp, dep,
                                          Wi_u, Ui_u, bi_u, Wf_u, Uf_u, bf_u,
                                          Wi_d, Ui_d, bi_d, Wf_d, Uf_d, bf_d,
                                          Bx, Upk, pb, x16);
    xp_gemm<<<256, 256, 0, stream>>>(x16, Bx, pb, XP);
    tree_kernel<<<1024, 256, 0, stream>>>(nb, nt, XP, Upk, out);

    (void)in_sizes; (void)n_in; (void)out_size; (void)ws_size;
}

// Round 15
// 196.079 us; speedup vs baseline: 1.0250x; 1.0250x over previous
//
#include <hip/hip_runtime.h>
#include <hip/hip_fp16.h>

// DepTreeLSTM on MI355X — R15 = R13 (best measured, 199.1 µs) + branch-free
// tanh (2*rcp(1+exp(-2x))-1) in the tree epilogue. No structural changes
// (R8/R11 codegen-cliff lesson: arithmetic-local edits only).
// prep: pack weights->fp16 (gate-interleaved), 768 blocks.
// xp_gemm: M=32 tiles / grid 1024, A staged directly from fp32 with cvt,
//   B via global_load_lds; XOR-8 granule swizzle.
// tree_kernel: 1024 blocks x 16 pairs, ping-pong LDS state, 1 lgkm-only
//   barrier/level, up-side XP prefetch one level ahead, U frags hoisted.

typedef _Float16 f16x8 __attribute__((ext_vector_type(8)));
typedef _Float16 f16x4 __attribute__((ext_vector_type(4)));
typedef float f32x4 __attribute__((ext_vector_type(4)));

#define NP 16   // pairs per tree block

__device__ __forceinline__ void async16(const void* g, void* l) {
    __builtin_amdgcn_global_load_lds(
        (const __attribute__((address_space(1))) void*)g,
        (__attribute__((address_space(3))) void*)l, 16, 0, 0);
}
__device__ __forceinline__ float sigm(float x) {
    return __builtin_amdgcn_rcpf(1.f + __expf(-x));
}
// branch-free tanh: 2/(1+e^{-2x}) - 1 ; exact limits at +/-inf.
__device__ __forceinline__ float ftanh(float x) {
    return __builtin_fmaf(2.f,
        __builtin_amdgcn_rcpf(1.f + __expf(-2.f * x)), -1.f);
}
__device__ __forceinline__ void lgkm_barrier() {
    asm volatile("s_waitcnt lgkmcnt(0)\n\ts_barrier" ::: "memory");
}

// ---- prep: pack weights/bias to fp16, gate-interleaved cols ----
__global__ __launch_bounds__(256) void prep_kernel(
    const float* __restrict__ Wi_u, const float* __restrict__ Ui_u,
    const float* __restrict__ bi_u, const float* __restrict__ Wf_u,
    const float* __restrict__ Uf_u, const float* __restrict__ bf_u,
    const float* __restrict__ Wi_d, const float* __restrict__ Ui_d,
    const float* __restrict__ bi_d, const float* __restrict__ Wf_d,
    const float* __restrict__ Uf_d, const float* __restrict__ bf_d,
    _Float16* __restrict__ Bx, _Float16* __restrict__ Upk,
    float* __restrict__ pb)
{
    int idx = blockIdx.x * 256 + threadIdx.x;     // 196608 total
    if (idx < 512) {
        int d = idx >> 8, c = idx & 255, u = c >> 2, g = c & 3;
        const float* bio = d ? bi_d : bi_u;
        const float* bf  = d ? bf_d : bf_u;
        pb[idx] = (g < 3) ? bio[g * 64 + u] : bf[u];
    }
    if (idx < 163840) {                            // Bx: [dir][col256][k320]
        int d = idx / 81920, r1 = idx % 81920;
        int c = r1 / 320, k = r1 % 320, u = c >> 2, g = c & 3;
        const float* Wio = d ? Wi_d : Wi_u;
        const float* Wf  = d ? Wf_d : Wf_u;
        Bx[idx] = (_Float16)((g < 3) ? Wio[k * 192 + g * 64 + u]
                                     : Wf[k * 64 + u]);
    } else {                                       // Upk: 2*4*64*64
        int j = idx - 163840;
        int d = j >> 14, r2 = j & 16383;
        int g = r2 >> 12, u = (r2 >> 6) & 63, k = r2 & 63;
        const float* Uio = d ? Ui_d : Ui_u;
        const float* Uf  = d ? Uf_d : Uf_u;
        Upk[j] = (_Float16)((g < 3) ? Uio[k * 192 + g * 64 + u]
                                    : Uf[k * 64 + u]);
    }
}

// ---- XP = [tok|oh|dep] @ Bx + pb : M=32 tiles, K=320, N=256; grid 1024 ----
__global__ __launch_bounds__(256, 2) void xp_gemm(
    const float* __restrict__ tok, const float* __restrict__ oh,
    const float* __restrict__ dep,
    const _Float16* __restrict__ Bx, const float* __restrict__ pb,
    _Float16* __restrict__ XP)
{
    __shared__ _Float16 At[32 * 64];      // 4 KB
    __shared__ _Float16 Btl[256 * 64];    // 32 KB
    const int dir = blockIdx.x & 1, mt = blockIdx.x >> 1;
    const int tid = threadIdx.x, lane = tid & 63, w = tid >> 6;
    const int l15 = lane & 15, qd = lane >> 4;
    const int rsub = lane >> 3, pg = lane & 7;
    const int kg = (pg - rsub) & 7;                  // logical granule in tile
    const int koff = kg * 8;
    const int rowbase = mt * 32;
    const _Float16* Bb = Bx + (size_t)dir * 81920 + (w * 64 + rsub) * 320 + koff;

    f32x4 acc[2][4];
    #pragma unroll
    for (int i = 0; i < 2; ++i)
        #pragma unroll
        for (int j = 0; j < 4; ++j) acc[i][j] = (f32x4){0.f, 0.f, 0.f, 0.f};

    #pragma unroll
    for (int kt = 0; kt < 5; ++kt) {
        // ---- A stage: fp32 source -> cvt -> swizzled LDS (1 row/lane) ----
        {
            int row = rowbase + w * 8 + rsub;              // bt index
            int g = kt * 8 + kg;                           // granule 0..39
            const float* src = (g < 32) ? tok + (size_t)row * 256 + g * 8
                             : (g < 36) ? oh  + (size_t)row * 32 + (g - 32) * 8
                                        : dep + (size_t)row * 32 + (g - 36) * 8;
            float4 f0 = *(const float4*)src;
            float4 f1 = *(const float4*)(src + 4);
            f16x8 v;
            v[0] = (_Float16)f0.x; v[1] = (_Float16)f0.y;
            v[2] = (_Float16)f0.z; v[3] = (_Float16)f0.w;
            v[4] = (_Float16)f1.x; v[5] = (_Float16)f1.y;
            v[6] = (_Float16)f1.z; v[7] = (_Float16)f1.w;
            *(f16x8*)&At[(w * 8 + rsub) * 64 + pg * 8] = v;
        }
        // ---- B stage: async16 from packed Bx ----
        #pragma unroll
        for (int is = 0; is < 8; ++is)
            async16(Bb + (size_t)is * 8 * 320 + kt * 64,
                    &Btl[(w * 64 + is * 8) * 64]);
        __syncthreads();
        #pragma unroll
        for (int s = 0; s < 2; ++s) {
            const int g0 = s * 4 + qd;
            f16x8 af[2];
            #pragma unroll
            for (int i = 0; i < 2; ++i) {
                int R = i * 16 + l15;
                af[i] = *(const f16x8*)&At[R * 64 + ((g0 + R) & 7) * 8];
            }
            #pragma unroll
            for (int j = 0; j < 4; ++j) {
                int C = j * 64 + w * 16 + l15;
                f16x8 bf = *(const f16x8*)&Btl[C * 64 + ((g0 + C) & 7) * 8];
                #pragma unroll
                for (int i = 0; i < 2; ++i)
                    acc[i][j] = __builtin_amdgcn_mfma_f32_16x16x32_f16(
                        af[i], bf, acc[i][j], 0, 0, 0);
            }
        }
        __syncthreads();
    }
    #pragma unroll
    for (int i = 0; i < 2; ++i)
        #pragma unroll
        for (int j = 0; j < 4; ++j) {
            int colp = j * 64 + w * 16 + l15;
            float bias = pb[dir * 256 + colp];
            #pragma unroll
            for (int r = 0; r < 4; ++r) {
                int row = rowbase + i * 16 + qd * 4 + r;
                XP[(size_t)row * 512 + dir * 256 + colp] =
                    (_Float16)(acc[i][j][r] + bias);
            }
        }
}

// ---- gather XP preacts for one side of one level into registers ----
template<int RPP>
__device__ __forceinline__ void gather_xp(
    const char* __restrict__ XPd, const int (*btl)[NP],
    int p0, int p1, int unit, int qd, f16x4* px)
{
    #pragma unroll
    for (int i = 0; i < RPP; ++i)
        #pragma unroll
        for (int r = 0; r < 4; ++r) {
            int row = i * 16 + qd * 4 + r;
            int pl  = (RPP == 2) ? (row >> 1) : row;
            int pos = (RPP == 2) ? ((row & 1) ? p1 : p0) : p0;
            px[i * 4 + r] = *(const f16x4*)(XPd + btl[pos][pl] + unit * 8);
        }
}

// ---- compute one side of one level (state read parity -> write parity) ----
template<int RPP>
__device__ __forceinline__ void side_level(
    const f16x8 (*bfr)[4], const f16x4* px,
    const _Float16 (*hR)[68], const _Float16 (*cR)[68],
    _Float16 (*hW)[68], _Float16 (*cW)[68],
    float* __restrict__ out, int pair0,
    int rs0, int rs1, int oc0, int oc1,
    int unit, int l15, int qd)
{
    f32x4 acc[RPP][4];
    #pragma unroll
    for (int i = 0; i < RPP; ++i)
        #pragma unroll
        for (int r = 0; r < 4; ++r) {
            f16x4 g4 = px[i * 4 + r];
            acc[i][0][r] = (float)g4[0];
            acc[i][1][r] = (float)g4[1];
            acc[i][2][r] = (float)g4[2];
            acc[i][3][r] = (float)g4[3];
        }

    if (rs0 >= 0) {
        #pragma unroll
        for (int s = 0; s < 2; ++s)
            #pragma unroll
            for (int i = 0; i < RPP; ++i) {
                int R = i * 16 + l15;
                int arow = (RPP == 2) ? ((R & ~1) | ((R & 1) ? rs1 : rs0))
                                      : (R * 2 + rs0);
                f16x8 af = *(const f16x8*)&hR[arow][s * 32 + qd * 8];
                #pragma unroll
                for (int g = 0; g < 4; ++g)
                    acc[i][g] = __builtin_amdgcn_mfma_f32_16x16x32_f16(
                        af, bfr[s][g], acc[i][g], 0, 0, 0);
            }
    }

    #pragma unroll
    for (int i = 0; i < RPP; ++i)
        #pragma unroll
        for (int r = 0; r < 4; ++r) {
            int row = i * 16 + qd * 4 + r;
            int pl   = (RPP == 2) ? (row >> 1) : row;
            int slot = (RPP == 2) ? (row & 1) : 0;
            int rs = slot ? rs1 : rs0;
            float cin = (rs >= 0) ? (float)cR[pl * 2 + rs][unit] : 0.f;
            float I = acc[i][0][r], O = acc[i][1][r],
                  Uu = acc[i][2][r], F = acc[i][3][r];
            float cn = sigm(I) * ftanh(Uu) + sigm(F) * cin;
            float h  = sigm(O) * ftanh(cn);
            int oc = slot ? oc1 : oc0;
            if (oc >= 0) {
                out[(size_t)(pair0 + pl) * 192 + oc + unit] = h;
            } else {
                hW[pl * 2 + slot][unit] = (_Float16)h;
                cW[pl * 2 + slot][unit] = (_Float16)cn;
            }
        }
}

// ---- root (up, t=8): h7/c7 from par0 slot0; h9/c9 from par1 slot1 ----
__device__ __forceinline__ void root_level(
    const f16x8 (*bfr)[4], const f16x4* px,
    const _Float16 (*hR0)[68], const _Float16 (*cR0)[68],
    const _Float16 (*hR1)[68], const _Float16 (*cR1)[68],
    float* __restrict__ out, int pair0, int unit, int l15, int qd)
{
    f32x4 aio[3], aF7, aF9;
    #pragma unroll
    for (int r = 0; r < 4; ++r) {
        f16x4 g4 = px[r];
        aio[0][r] = (float)g4[0];
        aio[1][r] = (float)g4[1];
        aio[2][r] = (float)g4[2];
        aF7[r] = (float)g4[3];
        aF9[r] = (float)g4[3];
    }
    #pragma unroll
    for (int s = 0; s < 2; ++s) {
        f16x8 v7 = *(const f16x8*)&hR0[l15 * 2 + 0][s * 32 + qd * 8];
        f16x8 v9 = *(const f16x8*)&hR1[l15 * 2 + 1][s * 32 + qd * 8];
        f16x8 vs = v7 + v9;
        aio[0] = __builtin_amdgcn_mfma_f32_16x16x32_f16(vs, bfr[s][0], aio[0], 0, 0, 0);
        aio[1] = __builtin_amdgcn_mfma_f32_16x16x32_f16(vs, bfr[s][1], aio[1], 0, 0, 0);
        aio[2] = __builtin_amdgcn_mfma_f32_16x16x32_f16(vs, bfr[s][2], aio[2], 0, 0, 0);
        aF7 = __builtin_amdgcn_mfma_f32_16x16x32_f16(v7, bfr[s][3], aF7, 0, 0, 0);
        aF9 = __builtin_amdgcn_mfma_f32_16x16x32_f16(v9, bfr[s][3], aF9, 0, 0, 0);
    }
    #pragma unroll
    for (int r = 0; r < 4; ++r) {
        int pl = qd * 4 + r;
        float c7 = (float)cR0[pl * 2 + 0][unit];
        float c9 = (float)cR1[pl * 2 + 1][unit];
        float cn = sigm(aio[0][r]) * ftanh(aio[2][r])
                 + sigm(aF7[r]) * c7 + sigm(aF9[r]) * c9;
        float h = sigm(aio[1][r]) * ftanh(cn);
        out[(size_t)(pair0 + pl) * 192 + unit] = h;
    }
}

__global__ __launch_bounds__(256, 2) void tree_kernel(
    const int* __restrict__ nb, const int* __restrict__ nt,
    const _Float16* __restrict__ XP, const _Float16* __restrict__ Upk,
    float* __restrict__ out)
{
    __shared__ _Float16 hS[2][2][NP * 2][68];  // [parity][dir][pl*2+slot][unit]
    __shared__ _Float16 cS[2][2][NP * 2][68];
    __shared__ int btl[16][NP];                // byte offsets into XP rows

    const int tid = threadIdx.x, lane = tid & 63, w = tid >> 6;
    const int l15 = lane & 15, qd = lane >> 4;
    const int unit = w * 16 + l15;
    const int pair0 = blockIdx.x * NP;

    {
        int pos = tid >> 4, pl = tid & 15;
        int node = (pair0 + pl) * 16 + pos;
        btl[pos][pl] = (nb[node] * 512 + nt[node]) * 1024;
    }

    // hoist U fragments for both dirs (register-resident, 64 VGPRs)
    f16x8 bU[2][4], bD[2][4];
    #pragma unroll
    for (int s = 0; s < 2; ++s)
        #pragma unroll
        for (int g = 0; g < 4; ++g) {
            bU[s][g] = *(const f16x8*)(Upk + (g * 64 + unit) * 64 + s * 32 + qd * 8);
            bD[s][g] = *(const f16x8*)(Upk + 16384 + (g * 64 + unit) * 64 + s * 32 + qd * 8);
        }

    __syncthreads();   // btl visible

    const char* XPu = (const char*)XP;
    const char* XPdn = XPu + 512;

    f16x4 pxu[2][8], pxd[8];
    gather_xp<2>(XPu, btl, 0, 15, unit, qd, pxu[0]);

    #pragma unroll
    for (int t = 0; t < 9; ++t) {
        const int pt = t & 1, pw = pt ^ 1;
        // prefetch down side for this level
        if (t == 0)      gather_xp<1>(XPdn, btl, 8, 8, unit, qd, pxd);
        else if (t == 8) gather_xp<1>(XPdn, btl, 0, 0, unit, qd, pxd);
        else             gather_xp<2>(XPdn, btl, 8 - t, 8 + t, unit, qd, pxd);
        // prefetch up side for next level (crosses the barrier)
        if (t < 6)       gather_xp<2>(XPu, btl, t + 1, 14 - t, unit, qd, pxu[pw]);
        else if (t == 6) gather_xp<1>(XPu, btl, 7, 7, unit, qd, pxu[pw]);
        else if (t == 7) gather_xp<1>(XPu, btl, 8, 8, unit, qd, pxu[pw]);

        // ---- up ----
        if (t < 7)
            side_level<2>(bU, pxu[pt], hS[pt][0], cS[pt][0],
                          hS[pw][0], cS[pw][0], out, pair0,
                          t ? 0 : -1, t ? 1 : -1, -1, -1, unit, l15, qd);
        else if (t == 7)
            side_level<1>(bU, pxu[pt], hS[pt][0], cS[pt][0],
                          hS[pw][0], cS[pw][0], out, pair0,
                          0, 0, -1, -1, unit, l15, qd);
        else
            root_level(bU, pxu[pt], hS[0][0], cS[0][0], hS[1][0], cS[1][0],
                       out, pair0, unit, l15, qd);

        // ---- down ----
        if (t == 0)
            side_level<1>(bD, pxd, hS[pt][1], cS[pt][1],
                          hS[pw][1], cS[pw][1], out, pair0,
                          -1, -1, -1, -1, unit, l15, qd);
        else if (t == 8)
            side_level<1>(bD, pxd, hS[pt][1], cS[pt][1],
                          hS[pw][1], cS[pw][1], out, pair0,
                          0, 0, 64, 64, unit, l15, qd);
        else
            side_level<2>(bD, pxd, hS[pt][1], cS[pt][1],
                          hS[pw][1], cS[pw][1], out, pair0,
                          0, (t == 1) ? 0 : 1, -1, (t == 7) ? 128 : -1,
                          unit, l15, qd);

        lgkm_barrier();   // LDS writes visible; global gathers stay in flight
    }
}

extern "C" void kernel_launch(void* const* d_in, const int* in_sizes, int n_in,
                              void* d_out, int out_size, void* d_ws, size_t ws_size,
                              hipStream_t stream)
{
    const float* tok  = (const float*)d_in[0];
    const float* ohp  = (const float*)d_in[1];
    const float* dep  = (const float*)d_in[2];
    const int*   nb   = (const int*)d_in[3];
    const int*   nt   = (const int*)d_in[4];
    const float* Wi_u = (const float*)d_in[13];
    const float* Ui_u = (const float*)d_in[14];
    const float* bi_u = (const float*)d_in[15];
    const float* Wf_u = (const float*)d_in[16];
    const float* Uf_u = (const float*)d_in[17];
    const float* bf_u = (const float*)d_in[18];
    const float* Wi_d = (const float*)d_in[19];
    const float* Ui_d = (const float*)d_in[20];
    const float* bi_d = (const float*)d_in[21];
    const float* Wf_d = (const float*)d_in[22];
    const float* Uf_d = (const float*)d_in[23];
    const float* bf_d = (const float*)d_in[24];

    char* ws = (char*)d_ws;
    _Float16* Bx  = (_Float16*)(ws);                    // 320 KB
    _Float16* Upk = (_Float16*)(ws + 0x50000);          // 64 KB
    float*    pb  = (float*)   (ws + 0x60000);          // 2 KB
    _Float16* XP  = (_Float16*)(ws + (12u << 20));      // 16 MB
    float* out = (float*)d_out;

    prep_kernel<<<768, 256, 0, stream>>>(Wi_u, Ui_u, bi_u, Wf_u, Uf_u, bf_u,
                                         Wi_d, Ui_d, bi_d, Wf_d, Uf_d, bf_d,
                                         Bx, Upk, pb);
    xp_gemm<<<1024, 256, 0, stream>>>(tok, ohp, dep, Bx, pb, XP);
    tree_kernel<<<1024, 256, 0, stream>>>(nb, nt, XP, Upk, out);

    (void)in_sizes; (void)n_in; (void)out_size; (void)ws_size;
}